// Round 5
// baseline (189.560 us; speedup 1.0000x reference)
//
#include <hip/hip_runtime.h>

#define NN 8192
#define EE 256
#define KNH 32
#define NKEEP 4096
#define TILE 2048
#define BUFCAP 192

typedef unsigned long long u64;
typedef unsigned int u32;

// ws layout (f32):
// gmpart : [2][32][256] f32 @ 0      (65536 B)
// gm     : [2][256]     f32 @ 65536  ( 2048 B)
// ld     : [2][8192]    f32 @ 67584  (65536 B)

__global__ void k_gm_partial(const float* __restrict__ x, float* __restrict__ part) {
    const int b = blockIdx.y, chunk = blockIdx.x, t = threadIdx.x;
    const float* xp = x + ((size_t)b * NN + (size_t)chunk * 256) * EE + t;
    float s = 0.0f;
    for (int i = 0; i < 256; ++i) s += xp[(size_t)i * EE];
    part[((size_t)b * 32 + chunk) * EE + t] = s;
}

__global__ void k_gm_final(const float* __restrict__ part, float* __restrict__ gm) {
    const int b = blockIdx.y, t = threadIdx.x;
    float s = 0.0f;
    for (int c = 0; c < 32; ++c) s += part[((size_t)b * 32 + c) * EE + t];
    gm[b * EE + t] = fabsf(s / (float)NN);
}

__device__ __forceinline__ u64 shfl_u64(u64 v, int src) {
    const u32 hi = (u32)__shfl((int)(u32)(v >> 32), src);
    const u32 lo = (u32)__shfl((int)(u32)v, src);
    return ((u64)hi << 32) | lo;
}

__device__ __forceinline__ u64 shfl_xor_u64(u64 v, int m) {
    const u32 hi = (u32)__shfl_xor((int)(u32)(v >> 32), m);
    const u32 lo = (u32)__shfl_xor((int)(u32)v, m);
    return ((u64)hi << 32) | lo;
}

// full bitonic sort of 64 u64 keys across lanes, ascending (lane 0 = min)
__device__ __forceinline__ u64 bitonic_sort64(u64 key, int lane) {
#pragma unroll
    for (int k = 2; k <= 64; k <<= 1) {
#pragma unroll
        for (int j = k >> 1; j > 0; j >>= 1) {
            const u64 other = shfl_xor_u64(key, j);
            const bool keep_min = (((lane & j) == 0) == ((lane & k) == 0));
            const bool lt = (key < other);
            const u64 mn = lt ? key : other;
            const u64 mx = lt ? other : key;
            key = keep_min ? mn : mx;
        }
    }
    return key;
}

// S, v both sorted ascending (64 each); return lowest 64 of union, sorted asc.
__device__ __forceinline__ u64 merge_low64(u64 S, u64 v, int lane) {
    const u64 vr = shfl_u64(v, 63 - lane);      // reverse v -> descending
    u64 m = (S < vr) ? S : vr;                  // half-cleaner: keep mins
#pragma unroll
    for (int j = 32; j > 0; j >>= 1) {          // m is bitonic -> 6-stage merge
        const u64 o = shfl_xor_u64(m, j);
        const bool keep_min = ((lane & j) == 0);
        const bool lt = (m < o);
        const u64 mn = lt ? m : o;
        const u64 mx = lt ? o : m;
        m = keep_min ? mn : mx;
    }
    return m;
}

// One wave per point: single-pass exact streaming top-32.
// Candidates with d_bits <= T32 (current exact 32nd-best) are ballot-compacted
// into a per-wave LDS buffer; at >=64 buffered, sort+merge into sorted top-64 S
// and tighten T32. Cap 192 > 63+128 -> overflow impossible -> exact always.
__global__ void k_knn_dist(const float* __restrict__ x, const float* __restrict__ coords,
                           const float* __restrict__ gm, float* __restrict__ ld_ws,
                           float* __restrict__ ld_out) {
    __shared__ float2 tile[TILE];
    __shared__ u64 buf[4][BUFCAP];
    const int b    = blockIdx.y;
    const int wid  = threadIdx.x >> 6;
    const int lane = threadIdx.x & 63;
    const int i    = blockIdx.x * 4 + wid;

    const float* cs0 = coords + (size_t)b * 2 * NN;
    const float* cs1 = cs0 + NN;
    const float ci0 = cs0[i];
    const float ci1 = cs1[i];
    const u64 lmask = (1ull << lane) - 1;

    u64 S   = ~0ull;            // sorted top-64 so far (lane m = m-th smallest)
    u32 T32 = 0xFFFFFFFFu;      // d-bits of current 32nd smallest
    int base = 0;               // buffered survivor count (wave-uniform)

    for (int tt = 0; tt < NN / TILE; ++tt) {
        __syncthreads();
#pragma unroll
        for (int k = 0; k < TILE / 256; ++k) {
            const int idx = tt * TILE + k * 256 + threadIdx.x;
            tile[k * 256 + threadIdx.x] = make_float2(cs0[idx], cs1[idx]);
        }
        __syncthreads();
        for (int t = 0; t < TILE / 128; ++t) {
            const float2 c0 = tile[t * 128 + lane];
            const float2 c1 = tile[t * 128 + 64 + lane];
            const float dx0 = ci0 - c0.x, dy0 = ci1 - c0.y;
            const float dx1 = ci0 - c1.x, dy1 = ci1 - c1.y;
            const float d0 = fmaf(dx0, dx0, dy0 * dy0);
            const float d1 = fmaf(dx1, dx1, dy1 * dy1);
            const u32 b0 = __float_as_uint(d0);
            const u32 b1 = __float_as_uint(d1);
            const bool p0 = (b0 <= T32);
            const bool p1 = (b1 <= T32);
            if (__any(p0 | p1)) {
                const int j0 = tt * TILE + t * 128 + lane;
                const u64 m0 = __ballot(p0);
                const u64 m1 = __ballot(p1);
                const int n0 = __popcll(m0);
                const int pos0 = base + __popcll(m0 & lmask);
                const int pos1 = base + n0 + __popcll(m1 & lmask);
                base += n0 + __popcll(m1);
                if (p0) buf[wid][pos0] = ((u64)b0 << 32) | (u32)j0;
                if (p1) buf[wid][pos1] = ((u64)b1 << 32) | (u32)(j0 + 64);
                if (base >= 64) {
                    const int nc = (base + 63) >> 6;
                    for (int c = 0; c < nc; ++c) {
                        const int idx2 = c * 64 + lane;
                        u64 v = (idx2 < base) ? buf[wid][idx2] : ~0ull;
                        v = bitonic_sort64(v, lane);
                        S = merge_low64(S, v, lane);
                    }
                    base = 0;
                    T32 = (u32)(shfl_u64(S, 31) >> 32);
                }
            }
        }
    }
    if (base > 0) {             // flush remaining survivors
        const int nc = (base + 63) >> 6;
        for (int c = 0; c < nc; ++c) {
            const int idx2 = c * 64 + lane;
            u64 v = (idx2 < base) ? buf[wid][idx2] : ~0ull;
            v = bitonic_sort64(v, lane);
            S = merge_low64(S, v, lane);
        }
    }
    const int jkeep = (int)(u32)S;   // lane m (m<32) holds m-th nearest index

    // ---- gather 32 rows, f32 sum/sumsq (4 channels per lane) ----
    float s1[4] = {0.f, 0.f, 0.f, 0.f};
    float s2[4] = {0.f, 0.f, 0.f, 0.f};
    const float* xb = x + (size_t)b * NN * EE;
#pragma unroll 8
    for (int k = 0; k < KNH; ++k) {
        const int j = __shfl(jkeep, k);
        const float4 v = *reinterpret_cast<const float4*>(xb + (size_t)j * EE + (lane << 2));
        s1[0] += v.x; s2[0] += v.x * v.x;
        s1[1] += v.y; s2[1] += v.y * v.y;
        s1[2] += v.z; s2[2] += v.z * v.z;
        s1[3] += v.w; s2[3] += v.w * v.w;
    }

    const float* gmb = gm + b * EE;
    float tt2 = 0.f;
#pragma unroll
    for (int q = 0; q < 4; ++q) {
        const float sum = s1[q];
        float ssd = s2[q] - sum * sum * (1.0f / 32.0f);
        ssd = ssd > 0.f ? ssd : 0.f;
        const float ls = sqrtf(ssd * (1.0f / 31.0f));
        tt2 += ls / gmb[(lane << 2) + q];
    }
#pragma unroll
    for (int s = 1; s < 64; s <<= 1) tt2 += __shfl_xor(tt2, s);

    if (lane == 0) {
        ld_ws [(size_t)b * NN + i] = tt2;
        ld_out[(size_t)b * NN + i] = tt2;
    }
}

// one wave per point: exact rank (desc, index tie-break) + direct row gather
__global__ void k_rank_gather(const float* __restrict__ x, const float* __restrict__ coords,
                              const float* __restrict__ ld,
                              float* __restrict__ x_out, float* __restrict__ c_out) {
    const int b    = blockIdx.y;
    const int wid  = threadIdx.x >> 6;
    const int lane = threadIdx.x & 63;
    const int i    = blockIdx.x * 4 + wid;
    const float* lb = ld + (size_t)b * NN;
    const float di = lb[i];
    int cnt = 0;
    for (int t = 0; t < NN / 64; ++t) {
        const int j = lane + t * 64;
        const float dj = lb[j];
        cnt += (dj > di || (dj == di && j < i)) ? 1 : 0;
    }
#pragma unroll
    for (int s = 1; s < 64; s <<= 1) cnt += __shfl_xor(cnt, s);

    if (cnt < NKEEP) {
        const float4 v = *reinterpret_cast<const float4*>(x + ((size_t)b * NN + i) * EE + (lane << 2));
        *reinterpret_cast<float4*>(x_out + ((size_t)b * NKEEP + cnt) * EE + (lane << 2)) = v;
        if (lane < 2) {
            c_out[((size_t)b * 2 + lane) * NKEEP + cnt] = coords[((size_t)b * 2 + lane) * NN + i];
        }
    }
}

extern "C" void kernel_launch(void* const* d_in, const int* in_sizes, int n_in,
                              void* d_out, int out_size, void* d_ws, size_t ws_size,
                              hipStream_t stream) {
    const float* x      = (const float*)d_in[0];
    const float* coords = (const float*)d_in[1];

    float* out    = (float*)d_out;
    float* x_out  = out;                 // [2][4096][256]
    float* c_out  = out + 2097152;       // [2][2][4096][1]
    float* ld_out = out + 2113536;       // [2][8192]

    char*  ws   = (char*)d_ws;
    float* part = (float*)(ws);
    float* gm   = (float*)(ws + 65536);
    float* ld   = (float*)(ws + 67584);

    k_gm_partial <<<dim3(32, 2),   256, 0, stream>>>(x, part);
    k_gm_final   <<<dim3(1, 2),    256, 0, stream>>>(part, gm);
    k_knn_dist   <<<dim3(2048, 2), 256, 0, stream>>>(x, coords, gm, ld, ld_out);
    k_rank_gather<<<dim3(2048, 2), 256, 0, stream>>>(x, coords, ld, x_out, c_out);
}

// Round 6
// 146.021 us; speedup vs baseline: 1.2982x; 1.2982x over previous
//
#include <hip/hip_runtime.h>

#define NN 8192
#define EE 256
#define KNH 32
#define NKEEP 4096
#define BUFCAP 72

typedef unsigned long long u64;
typedef unsigned int u32;

// ws layout (f32):
// gmpart : [2][32][256] f32 @ 0      (65536 B)
// gm     : [2][256]     f32 @ 65536  ( 2048 B)
// ld     : [2][8192]    f32 @ 67584  (65536 B)

__global__ void k_gm_partial(const float* __restrict__ x, float* __restrict__ part) {
    const int b = blockIdx.y, chunk = blockIdx.x, t = threadIdx.x;
    const float* xp = x + ((size_t)b * NN + (size_t)chunk * 256) * EE + t;
    float s = 0.0f;
    for (int i = 0; i < 256; ++i) s += xp[(size_t)i * EE];
    part[((size_t)b * 32 + chunk) * EE + t] = s;
}

__global__ void k_gm_final(const float* __restrict__ part, float* __restrict__ gm) {
    const int b = blockIdx.y, t = threadIdx.x;
    float s = 0.0f;
    for (int c = 0; c < 32; ++c) s += part[((size_t)b * 32 + c) * EE + t];
    gm[b * EE + t] = fabsf(s / (float)NN);
}

__device__ __forceinline__ u64 shfl_xor_u64(u64 v, int m) {
    const u32 hi = (u32)__shfl_xor((int)(u32)(v >> 32), m);
    const u32 lo = (u32)__shfl_xor((int)(u32)v, m);
    return ((u64)hi << 32) | lo;
}

__device__ __forceinline__ u64 wave_min_u64(u64 h) {
#pragma unroll
    for (int s = 1; s < 64; s <<= 1) {
        const u64 o = shfl_xor_u64(h, s);
        h = (o < h) ? o : h;
    }
    return h;
}

// One wave per point. Pass1: per-lane top-2 f32 distances (float4 coord loads,
// 4 cands/lane/iter). T = 32nd smallest of kept (ballot binary search) >= d32.
// Pass2: branchless ballot-compaction of all d<=T into per-wave LDS, bitonic
// sort -> exact top-32 by (d,j). Certificate base>64 -> exact fallback.
__global__ void k_knn_dist(const float* __restrict__ x, const float* __restrict__ coords,
                           const float* __restrict__ gm, float* __restrict__ ld_ws,
                           float* __restrict__ ld_out) {
    __shared__ u64 buf[4][BUFCAP];
    const int b    = blockIdx.y;
    const int wid  = threadIdx.x >> 6;
    const int lane = threadIdx.x & 63;
    const int i    = blockIdx.x * 4 + wid;

    const float* cs0 = coords + (size_t)b * 2 * NN;
    const float* cs1 = cs0 + NN;
    const float ci0 = cs0[i];
    const float ci1 = cs1[i];

    // ---- pass 1: per-lane top-2 distances ----
    float K0 = 1e30f, K1 = 1e30f;
#define INS2(d)                                          \
    do {                                                 \
        const float _d = (d);                            \
        K1 = (_d < K0) ? K0 : ((_d < K1) ? _d : K1);     \
        K0 = fminf(_d, K0);                              \
    } while (0)

#pragma unroll 4
    for (int t = 0; t < NN / 256; ++t) {
        const int j = t * 256 + (lane << 2);
        const float4 xa = *reinterpret_cast<const float4*>(cs0 + j);
        const float4 ya = *reinterpret_cast<const float4*>(cs1 + j);
        const float dx0 = ci0 - xa.x, dy0 = ci1 - ya.x;
        const float dx1 = ci0 - xa.y, dy1 = ci1 - ya.y;
        const float dx2 = ci0 - xa.z, dy2 = ci1 - ya.z;
        const float dx3 = ci0 - xa.w, dy3 = ci1 - ya.w;
        const float d0 = fmaf(dx0, dx0, dy0 * dy0);
        const float d1 = fmaf(dx1, dx1, dy1 * dy1);
        const float d2 = fmaf(dx2, dx2, dy2 * dy2);
        const float d3 = fmaf(dx3, dx3, dy3 * dy3);
        INS2(d0); INS2(d1); INS2(d2); INS2(d3);
    }

    // ---- threshold: minimal T with count(kept_bits <= T) >= 32 ----
    const u32 k0 = __float_as_uint(K0), k1 = __float_as_uint(K1);
    u32 lo = 0, hi = 0xFFFFFFFFu;
    for (int it = 0; it < 32; ++it) {
        const u32 mid = lo + ((hi - lo) >> 1);
        const int c = __popcll(__ballot(k0 <= mid)) + __popcll(__ballot(k1 <= mid));
        if (c >= KNH) hi = mid; else lo = mid + 1;
    }
    const u32 T = hi;

    // ---- pass 2: branchless compaction of all d_bits <= T ----
    const u64 lmask = (1ull << lane) - 1;
    int base = 0;
#pragma unroll 4
    for (int t = 0; t < NN / 256; ++t) {
        const int j = t * 256 + (lane << 2);
        const float4 xa = *reinterpret_cast<const float4*>(cs0 + j);
        const float4 ya = *reinterpret_cast<const float4*>(cs1 + j);
        const float dx0 = ci0 - xa.x, dy0 = ci1 - ya.x;
        const float dx1 = ci0 - xa.y, dy1 = ci1 - ya.y;
        const float dx2 = ci0 - xa.z, dy2 = ci1 - ya.z;
        const float dx3 = ci0 - xa.w, dy3 = ci1 - ya.w;
        const u32 b0 = __float_as_uint(fmaf(dx0, dx0, dy0 * dy0));
        const u32 b1 = __float_as_uint(fmaf(dx1, dx1, dy1 * dy1));
        const u32 b2 = __float_as_uint(fmaf(dx2, dx2, dy2 * dy2));
        const u32 b3 = __float_as_uint(fmaf(dx3, dx3, dy3 * dy3));
        const bool p0 = (b0 <= T), p1 = (b1 <= T), p2 = (b2 <= T), p3 = (b3 <= T);
        const u64 m0 = __ballot(p0), m1 = __ballot(p1), m2 = __ballot(p2), m3 = __ballot(p3);
        const int n0 = __popcll(m0), n1 = __popcll(m1), n2 = __popcll(m2), n3 = __popcll(m3);
        const int pos0 = base + __popcll(m0 & lmask);
        const int pos1 = base + n0 + __popcll(m1 & lmask);
        const int pos2 = base + n0 + n1 + __popcll(m2 & lmask);
        const int pos3 = base + n0 + n1 + n2 + __popcll(m3 & lmask);
        base += n0 + n1 + n2 + n3;
        if (p0 && pos0 < 64) buf[wid][pos0] = ((u64)b0 << 32) | (u32)j;
        if (p1 && pos1 < 64) buf[wid][pos1] = ((u64)b1 << 32) | (u32)(j + 1);
        if (p2 && pos2 < 64) buf[wid][pos2] = ((u64)b2 << 32) | (u32)(j + 2);
        if (p3 && pos3 < 64) buf[wid][pos3] = ((u64)b3 << 32) | (u32)(j + 3);
    }
    const bool ovf = (base > 64);
    const int nb = ovf ? 64 : base;

    // ---- bitonic sort (ascending) of up to 64 keys across lanes ----
    u64 key = (lane < nb) ? buf[wid][lane] : ~0ull;
#pragma unroll
    for (int k = 2; k <= 64; k <<= 1) {
#pragma unroll
        for (int j = k >> 1; j > 0; j >>= 1) {
            const u64 other = shfl_xor_u64(key, j);
            const bool keep_min = (((lane & j) == 0) == ((lane & k) == 0));
            const bool lt = (key < other);
            const u64 mn = lt ? key : other;
            const u64 mx = lt ? other : key;
            key = keep_min ? mn : mx;
        }
    }
    int jkeep = (int)(u32)key;   // lane m (m<32) holds m-th nearest index

    // ---- certificate fallback (exact restream), ~never taken ----
    if (ovf) {
        u64 minkeep = 0;
        for (int k = 0; k < KNH; ++k) {
            u64 best = ~0ull;
            for (int t = 0; t < NN / 64; ++t) {
                const int j = lane + t * 64;
                const float dx = ci0 - cs0[j];
                const float dy = ci1 - cs1[j];
                const float d  = fmaf(dx, dx, dy * dy);
                const u64 kk = ((u64)__float_as_uint(d) << 32) | (u32)j;
                if (kk >= minkeep && kk < best) best = kk;
            }
            const u64 h = wave_min_u64(best);
            if (lane == k) jkeep = (int)(u32)h;
            minkeep = h + 1;
        }
    }

    // ---- gather 32 rows, f32 sum/sumsq (4 channels per lane) ----
    float s1[4] = {0.f, 0.f, 0.f, 0.f};
    float s2[4] = {0.f, 0.f, 0.f, 0.f};
    const float* xb = x + (size_t)b * NN * EE;
#pragma unroll 8
    for (int k = 0; k < KNH; ++k) {
        const int j = __shfl(jkeep, k);
        const float4 v = *reinterpret_cast<const float4*>(xb + (size_t)j * EE + (lane << 2));
        s1[0] += v.x; s2[0] += v.x * v.x;
        s1[1] += v.y; s2[1] += v.y * v.y;
        s1[2] += v.z; s2[2] += v.z * v.z;
        s1[3] += v.w; s2[3] += v.w * v.w;
    }

    const float* gmb = gm + b * EE;
    float tt = 0.f;
#pragma unroll
    for (int q = 0; q < 4; ++q) {
        const float sum = s1[q];
        float ssd = s2[q] - sum * sum * (1.0f / 32.0f);
        ssd = ssd > 0.f ? ssd : 0.f;
        const float ls = sqrtf(ssd * (1.0f / 31.0f));
        tt += ls / gmb[(lane << 2) + q];
    }
#pragma unroll
    for (int s = 1; s < 64; s <<= 1) tt += __shfl_xor(tt, s);

    if (lane == 0) {
        ld_ws [(size_t)b * NN + i] = tt;
        ld_out[(size_t)b * NN + i] = tt;
    }
}

// one wave per point: exact rank (desc, index tie-break) + direct row gather
__global__ void k_rank_gather(const float* __restrict__ x, const float* __restrict__ coords,
                              const float* __restrict__ ld,
                              float* __restrict__ x_out, float* __restrict__ c_out) {
    const int b    = blockIdx.y;
    const int wid  = threadIdx.x >> 6;
    const int lane = threadIdx.x & 63;
    const int i    = blockIdx.x * 4 + wid;
    const float* lb = ld + (size_t)b * NN;
    const float di = lb[i];
    int cnt = 0;
    for (int t = 0; t < NN / 64; ++t) {
        const int j = lane + t * 64;
        const float dj = lb[j];
        cnt += (dj > di || (dj == di && j < i)) ? 1 : 0;
    }
#pragma unroll
    for (int s = 1; s < 64; s <<= 1) cnt += __shfl_xor(cnt, s);

    if (cnt < NKEEP) {
        const float4 v = *reinterpret_cast<const float4*>(x + ((size_t)b * NN + i) * EE + (lane << 2));
        *reinterpret_cast<float4*>(x_out + ((size_t)b * NKEEP + cnt) * EE + (lane << 2)) = v;
        if (lane < 2) {
            c_out[((size_t)b * 2 + lane) * NKEEP + cnt] = coords[((size_t)b * 2 + lane) * NN + i];
        }
    }
}

extern "C" void kernel_launch(void* const* d_in, const int* in_sizes, int n_in,
                              void* d_out, int out_size, void* d_ws, size_t ws_size,
                              hipStream_t stream) {
    const float* x      = (const float*)d_in[0];
    const float* coords = (const float*)d_in[1];

    float* out    = (float*)d_out;
    float* x_out  = out;                 // [2][4096][256]
    float* c_out  = out + 2097152;       // [2][2][4096][1]
    float* ld_out = out + 2113536;       // [2][8192]

    char*  ws   = (char*)d_ws;
    float* part = (float*)(ws);
    float* gm   = (float*)(ws + 65536);
    float* ld   = (float*)(ws + 67584);

    k_gm_partial <<<dim3(32, 2),   256, 0, stream>>>(x, part);
    k_gm_final   <<<dim3(1, 2),    256, 0, stream>>>(part, gm);
    k_knn_dist   <<<dim3(2048, 2), 256, 0, stream>>>(x, coords, gm, ld, ld_out);
    k_rank_gather<<<dim3(2048, 2), 256, 0, stream>>>(x, coords, ld, x_out, c_out);
}